// Round 15
// baseline (239.652 us; speedup 1.0000x reference)
//
#include <hip/hip_runtime.h>
#include <stdint.h>

// Problem constants (N,C,H,W fixed by the reference)
#define NB 32
#define CH 256
#define HH 56
#define WW 56
#define HWSZ (HH*WW)            // 3136
#define NPIX (NB*HWSZ)          // 100352
#define HP 58
#define WP 58
#define PADPIX (NB*HP*WP)       // 107648
#define NTAPS 9
#define KKE (CH*NTAPS)          // 2304
#define NPIXD 100352.0
#define WQ_CONV (NTAPS*8*8*64*16)   // 589824 bytes of prepacked weights per conv
#define HSTRIDE 272             // halo row stride

typedef int int4v  __attribute__((ext_vector_type(4)));
typedef int int16v __attribute__((ext_vector_type(16)));
typedef unsigned int uint4v __attribute__((ext_vector_type(4)));

// ---------------- init: zero stats accumulators (8-way split) ----------------
__global__ void init_kernel(long long* __restrict__ sums8) {
    int t = blockIdx.x*256 + threadIdx.x;
    if (t < 2*8*512) sums8[t] = 0;     // 2 convs x 8 splits x 256 ch x {sum,sumsq}
}

// ---------------- prepack weights into MFMA B-fragment layout ----------------
__global__ void wqpack_kernel(const float* __restrict__ w1, const float* __restrict__ w2,
                              int8_t* __restrict__ wq) {
    int t = blockIdx.x*256 + threadIdx.x;     // 144 blocks -> 36864 threads
    int conv = blockIdx.y;
    const float* w = conv ? w2 : w1;
    int lane = t & 63;
    int g = t >> 6;                 // (tap*8+ks)*8+nb
    int nb = g & 7, h = g >> 3;
    int ks = h & 7, tap = h >> 3;
    int o = nb*32 + (lane & 31);
    int cin0 = ks*32 + (lane >> 5)*16;
    int wd[4];
    #pragma unroll
    for (int q = 0; q < 4; ++q) {
        int wv = 0;
        #pragma unroll
        for (int j = 0; j < 4; ++j) {
            float v = w[(size_t)(o*CH + cin0 + q*4 + j)*NTAPS + tap];
            int s = (v > 0.f) ? 1 : ((v < 0.f) ? -1 : 0);
            wv |= (s & 0xff) << (8*j);
        }
        wd[q] = wv;
    }
    *(int4v*)(wq + (size_t)conv*WQ_CONV + (size_t)t*16) = (int4v){wd[0], wd[1], wd[2], wd[3]};
}

// ---------------- alpha[o] = mean |w| over (I,3,3) ----------------
__global__ void alpha_kernel(const float* __restrict__ w1, const float* __restrict__ w2,
                             float* __restrict__ alpha) {
    int o = blockIdx.x; int conv = blockIdx.y;
    const float* w = conv ? w2 : w1;
    float s = 0.f;
    for (int i = threadIdx.x; i < KKE; i += 256) s += fabsf(w[(size_t)o*KKE + i]);
    for (int off = 32; off; off >>= 1) s += __shfl_down(s, off);
    __shared__ float l[4];
    int lane = threadIdx.x & 63, wv = threadIdx.x >> 6;
    if (lane == 0) l[wv] = s;
    __syncthreads();
    if (threadIdx.x == 0) alpha[conv*CH + o] = (l[0]+l[1]+l[2]+l[3]) * (1.f/KKE);
}

// ---------------- pack activations: x -> int8 sign, padded, ch-contiguous ----------------
__global__ void pack_x_kernel(const float* __restrict__ x, int8_t* __restrict__ apad) {
    int p = blockIdx.x*256 + threadIdx.x;
    if (p >= PADPIX) return;
    int n  = p / (HP*WP);
    int r  = p - n*(HP*WP);
    int hp = r / WP, wp = r - hp*WP;
    int4v* dst = (int4v*)(apad + (size_t)p*CH);
    if (hp >= 1 && hp <= HH && wp >= 1 && wp <= WW) {
        const float* xb = x + (size_t)n*CH*HWSZ + (hp-1)*WW + (wp-1);
        #pragma unroll 2
        for (int c16 = 0; c16 < 16; ++c16) {
            int wd[4];
            #pragma unroll
            for (int q = 0; q < 4; ++q) {
                int wv = 0;
                #pragma unroll
                for (int j = 0; j < 4; ++j) {
                    float v = xb[(size_t)(c16*16 + q*4 + j)*HWSZ];
                    int s = (v > 0.f) ? 1 : ((v < 0.f) ? -1 : 0);
                    wv |= (s & 0xff) << (8*j);
                }
                wd[q] = wv;
            }
            dst[c16] = (int4v){wd[0], wd[1], wd[2], wd[3]};
        }
    } else {
        int4v z = {0,0,0,0};
        #pragma unroll
        for (int c16 = 0; c16 < 16; ++c16) dst[c16] = z;
    }
}

// ---------------- int8 MFMA implicit-GEMM 3x3 conv, asm-pipelined, 2-img blocks ---------
// 784 blocks x 256 threads; block = 2 images x 8x8 pixels x 256 ch.
// wave = 4 M-subtiles (2/img) x 64 ch: per iter 4 ds_read + 2 buffer_load + 8 MFMA
// (2x the MFMA per load-issue of the 1-img shape). Asm ring depth 2 (T3/T4/T8,
// rule #18) keeps loads 2 iters ahead; chunk-XOR swizzle on halo.
#define ISSUE_SET(IT) do { \
        int k_ = (IT) % 3; \
        int tap_ = (IT) >> 3; \
        int toff_ = (tap_/3)*10 + (tap_ - (tap_/3)*3); \
        int ch_ = 2*((IT) & 7) + kh; \
        int p0_ = pix0 + toff_; \
        int p1_ = p0_ + 40; \
        int p2_ = p0_ + 100; \
        int p3_ = p1_ + 100; \
        uint32_t ad0_ = halob + (uint32_t)(p0_*HSTRIDE + ((ch_ ^ ((p0_>>3)&7)) << 4)); \
        uint32_t ad1_ = halob + (uint32_t)(p1_*HSTRIDE + ((ch_ ^ ((p1_>>3)&7)) << 4)); \
        uint32_t ad2_ = halob + (uint32_t)(p2_*HSTRIDE + ((ch_ ^ ((p2_>>3)&7)) << 4)); \
        uint32_t ad3_ = halob + (uint32_t)(p3_*HSTRIDE + ((ch_ ^ ((p3_>>3)&7)) << 4)); \
        uint32_t vo_ = voff + (uint32_t)(IT)*8192u; \
        asm volatile("ds_read_b128 %0, %1" : "=v"(as_[k_][0]) : "v"(ad0_)); \
        asm volatile("ds_read_b128 %0, %1" : "=v"(as_[k_][1]) : "v"(ad1_)); \
        asm volatile("ds_read_b128 %0, %1" : "=v"(as_[k_][2]) : "v"(ad2_)); \
        asm volatile("ds_read_b128 %0, %1" : "=v"(as_[k_][3]) : "v"(ad3_)); \
        asm volatile("buffer_load_dwordx4 %0, %1, %2, 0 offen" \
                     : "=v"(bs_[k_][0]) : "v"(vo_), "s"(rsrc)); \
        asm volatile("buffer_load_dwordx4 %0, %1, %2, 0 offen offset:1024" \
                     : "=v"(bs_[k_][1]) : "v"(vo_), "s"(rsrc)); \
    } while (0)

#define CONV_BODY \
    __syncthreads(); \
    int lane = t & 63; \
    int nbp = __builtin_amdgcn_readfirstlane(t >> 6); \
    int kh = lane >> 5, lr = lane & 31; \
    int r0 = lr >> 3, c0 = lr & 7; \
    int pix0 = r0*10 + c0; \
    uint32_t halob = (uint32_t)(uintptr_t)halo; \
    uint32_t voff = (uint32_t)(nbp*2048 + lane*16); \
    uint4v rsrc; \
    { union { const int8_t* p; unsigned long long u; } pu_; pu_.p = wq; \
      rsrc.x = (unsigned)pu_.u; rsrc.y = (unsigned)(pu_.u >> 32); \
      rsrc.z = 0xffffffffu; rsrc.w = 0x00020000u; } \
    int4v as_[3][4], bs_[3][2]; \
    int16v acc00, acc01, acc10, acc11, acc20, acc21, acc30, acc31; \
    _Pragma("unroll") \
    for (int i = 0; i < 16; ++i) { \
        acc00[i]=0; acc01[i]=0; acc10[i]=0; acc11[i]=0; \
        acc20[i]=0; acc21[i]=0; acc30[i]=0; acc31[i]=0; \
    } \
    ISSUE_SET(0); \
    ISSUE_SET(1); \
    _Pragma("unroll") \
    for (int it = 0; it < 72; ++it) { \
        if (it + 1 < 72) { asm volatile("s_waitcnt lgkmcnt(4) vmcnt(2)"); } \
        else             { asm volatile("s_waitcnt lgkmcnt(0) vmcnt(0)"); } \
        __builtin_amdgcn_sched_barrier(0); \
        if (it + 2 < 72) { ISSUE_SET(it + 2); } \
        int kc_ = it % 3; \
        acc00 = __builtin_amdgcn_mfma_i32_32x32x32_i8(as_[kc_][0], bs_[kc_][0], acc00, 0,0,0); \
        acc01 = __builtin_amdgcn_mfma_i32_32x32x32_i8(as_[kc_][0], bs_[kc_][1], acc01, 0,0,0); \
        acc10 = __builtin_amdgcn_mfma_i32_32x32x32_i8(as_[kc_][1], bs_[kc_][0], acc10, 0,0,0); \
        acc11 = __builtin_amdgcn_mfma_i32_32x32x32_i8(as_[kc_][1], bs_[kc_][1], acc11, 0,0,0); \
        acc20 = __builtin_amdgcn_mfma_i32_32x32x32_i8(as_[kc_][2], bs_[kc_][0], acc20, 0,0,0); \
        acc21 = __builtin_amdgcn_mfma_i32_32x32x32_i8(as_[kc_][2], bs_[kc_][1], acc21, 0,0,0); \
        acc30 = __builtin_amdgcn_mfma_i32_32x32x32_i8(as_[kc_][3], bs_[kc_][0], acc30, 0,0,0); \
        acc31 = __builtin_amdgcn_mfma_i32_32x32x32_i8(as_[kc_][3], bs_[kc_][1], acc31, 0,0,0); \
    } \
    { \
        int s1a = 0, s2a = 0, s1b = 0, s2b = 0; \
        _Pragma("unroll") \
        for (int reg = 0; reg < 16; ++reg) { \
            int row_ = (reg & 3) + 8*(reg >> 2) + 4*kh; \
            _Pragma("unroll") \
            for (int mm = 0; mm < 4; ++mm) { \
                int img_ = mm >> 1; \
                int pm_ = (mm & 1)*32 + row_; \
                int rr_ = pm_ >> 3, cc_ = pm_ & 7; \
                size_t pbase_ = (size_t)(((n0+img_)*HH + ty*8 + rr_)*WW + tx*8 + cc_)*CH; \
                int v0, v1; \
                if (mm == 0)      { v0 = acc00[reg]; v1 = acc01[reg]; } \
                else if (mm == 1) { v0 = acc10[reg]; v1 = acc11[reg]; } \
                else if (mm == 2) { v0 = acc20[reg]; v1 = acc21[reg]; } \
                else              { v0 = acc30[reg]; v1 = acc31[reg]; } \
                cnt[pbase_ + (nbp*2+0)*32 + lr] = (int16_t)v0; \
                cnt[pbase_ + (nbp*2+1)*32 + lr] = (int16_t)v1; \
                s1a += v0; s2a += v0*v0; s1b += v1; s2b += v1*v1; \
            } \
        } \
        s1a += __shfl_down(s1a, 32); s2a += __shfl_down(s2a, 32); \
        s1b += __shfl_down(s1b, 32); s2b += __shfl_down(s2b, 32); \
        if (lane < 32) { \
            long long* sp = sums8 + (size_t)(b & 7)*512; \
            int ch0 = nbp*64 + lr, ch1 = ch0 + 32; \
            atomicAdd((unsigned long long*)&sp[2*ch0],   (unsigned long long)(long long)s1a); \
            atomicAdd((unsigned long long*)&sp[2*ch0+1], (unsigned long long)(long long)s2a); \
            atomicAdd((unsigned long long*)&sp[2*ch1],   (unsigned long long)(long long)s1b); \
            atomicAdd((unsigned long long*)&sp[2*ch1+1], (unsigned long long)(long long)s2b); \
        } \
    }

__global__ __launch_bounds__(256, 2) void conv_kernel(
        const int8_t* __restrict__ apad, const int8_t* __restrict__ wq,
        int16_t* __restrict__ cnt, long long* __restrict__ sums8) {
    __shared__ __attribute__((aligned(16))) int8_t halo[200*HSTRIDE];   // 54.4 KB
    int b = blockIdx.x;                           // 784 = 16 image-pairs x 49 tiles
    int tile = b % 49, npair = b / 49;
    int ty = tile / 7, tx = tile % 7;
    int n0 = npair * 2;
    int t = threadIdx.x;

    // stage halo: 200 pixels x 16 chunks of 16B, chunk index swizzled
    #pragma unroll 1
    for (int j = 0; j < 13; ++j) {
        int idx = t + j*256;
        if (idx < 3200) {
            int pix = idx >> 4, c16 = idx & 15;
            int img = (pix >= 100) ? 1 : 0;
            int hp = pix - img*100;
            int dr = hp / 10, dc = hp - dr*10;
            const int4v* src = (const int4v*)(apad +
                ((size_t)(((n0+img)*HP + ty*8+dr)*WP + tx*8+dc))*CH + c16*16);
            *(int4v*)&halo[pix*HSTRIDE + ((c16 ^ ((pix >> 3) & 7)) << 4)] = *src;
        }
    }
    CONV_BODY
}

// ---------------- conv2: same hot loop, staging fuses BN1+sign from int16 cnt1 ----------
__global__ __launch_bounds__(256, 2) void conv2_kernel(
        const int16_t* __restrict__ src16, const float* __restrict__ ab,
        const int8_t* __restrict__ wq,
        int16_t* __restrict__ cnt, long long* __restrict__ sums8) {
    __shared__ __attribute__((aligned(16))) int8_t halo[200*HSTRIDE];   // 54.4 KB
    int b = blockIdx.x;                           // 784 = 16 image-pairs x 49 tiles
    int tile = b % 49, npair = b / 49;
    int ty = tile / 7, tx = tile % 7;
    int n0 = npair * 2;
    int t = threadIdx.x;

    // stage halo with inline BN1+sign (identical math to the old pack_s), swizzled
    {
        int c16s = t & 15;
        #pragma unroll 1
        for (int k = 0; k < 13; ++k) {
            int pix = (t >> 4) + k*16;
            if (pix < 200) {
                int img = (pix >= 100) ? 1 : 0;
                int hp = pix - img*100;
                int dr = hp / 10, dc = hp - dr*10;
                int hi = ty*8 + dr - 1, wi = tx*8 + dc - 1;
                int4v outv = {0,0,0,0};
                if ((unsigned)hi < (unsigned)HH && (unsigned)wi < (unsigned)WW) {
                    const int16_t* sp = src16 + ((size_t)((n0+img)*HH + hi)*WW + wi)*CH + c16s*16;
                    int4v u0 = *(const int4v*)sp;
                    int4v u1 = *(const int4v*)(sp + 8);
                    int wd[4];
                    #pragma unroll
                    for (int q = 0; q < 4; ++q) {
                        int wv = 0;
                        #pragma unroll
                        for (int j = 0; j < 4; ++j) {
                            int e = q*4 + j;
                            int word = (e < 8) ? u0[e >> 1] : u1[(e-8) >> 1];
                            int sval = (e & 1) ? (word >> 16) : ((word << 16) >> 16);
                            int ch = c16s*16 + e;
                            float v = fmaf(ab[ch], (float)sval, ab[CH + ch]);
                            int s = (v > 0.f) ? 1 : ((v < 0.f) ? -1 : 0);
                            wv |= (s & 0xff) << (8*j);
                        }
                        wd[q] = wv;
                    }
                    outv = (int4v){wd[0], wd[1], wd[2], wd[3]};
                }
                *(int4v*)&halo[pix*HSTRIDE + ((c16s ^ ((pix >> 3) & 7)) << 4)] = outv;
            }
        }
    }
    CONV_BODY
}

// ---------------- BN coefficients: BN(alpha*cnt) = a*cnt + b ----------------
__global__ void bncoef_kernel(const long long* __restrict__ sums8,
                              const float* __restrict__ alpha,
                              const float* __restrict__ gamma, const float* __restrict__ beta,
                              float* __restrict__ ab) {
    int o = threadIdx.x;
    long long S1i = 0, S2i = 0;
    #pragma unroll
    for (int k = 0; k < 8; ++k) {
        S1i += sums8[(size_t)k*512 + 2*o];
        S2i += sums8[(size_t)k*512 + 2*o + 1];
    }
    double S1 = (double)S1i, S2 = (double)S2i;
    double mean = S1 / NPIXD;
    double var  = S2 / NPIXD - mean*mean;
    double al   = (double)alpha[o];
    double rs   = 1.0 / sqrt(al*al*var + 1e-5);
    double a    = (double)gamma[o] * al * rs;
    ab[o]      = (float)a;
    ab[CH + o] = (float)((double)beta[o] - a*mean);
}

// ---------------- fused epilogue: out = a2*cnt2 + b2 + x  (LDS transpose) ----------------
__global__ __launch_bounds__(256) void final_kernel(const int16_t* __restrict__ cnt,
        const float* __restrict__ x, const float* __restrict__ ab, float* __restrict__ out) {
    __shared__ int4v lsd4[64*32];                 // 64 pixels x 512B, swizzled
    int8_t* lb = (int8_t*)lsd4;
    int b = blockIdx.x;                           // 1568 = 32 n x 49 tiles
    int n = b / 49, tile = b - n*49;
    int p0 = tile * 64;
    int t = threadIdx.x;
    const int4v* src = (const int4v*)(cnt + ((size_t)n*HWSZ + p0)*CH);
    #pragma unroll
    for (int j = 0; j < 8; ++j) {
        int c = t + j*256;                        // 2048 16B-chunks
        int pix = c >> 5, c16 = c & 31;
        *(int4v*)&lb[pix*512 + ((c16*16) ^ ((pix & 15) << 4))] = src[c];
    }
    __syncthreads();
    int pixL = t & 63;
    int cb = (t >> 6) * 64;
    #pragma unroll 1
    for (int i = 0; i < 8; ++i) {
        int ch0 = cb + i*8;
        int4v v = *(const int4v*)&lb[pixL*512 + ((ch0*2) ^ ((pixL & 15) << 4))];
        #pragma unroll
        for (int j = 0; j < 8; ++j) {
            int ch = ch0 + j;
            int word = v[j >> 1];
            int sval = (j & 1) ? (word >> 16) : ((word << 16) >> 16);
            size_t g = (size_t)(n*CH + ch)*HWSZ + p0 + pixL;
            out[g] = fmaf(ab[ch], (float)sval, ab[CH + ch]) + x[g];
        }
    }
}

extern "C" void kernel_launch(void* const* d_in, const int* in_sizes, int n_in,
                              void* d_out, int out_size, void* d_ws, size_t ws_size,
                              hipStream_t stream) {
    const float* x  = (const float*)d_in[0];
    const float* w1 = (const float*)d_in[1];
    const float* g1 = (const float*)d_in[2];
    const float* b1 = (const float*)d_in[3];
    const float* w2 = (const float*)d_in[4];
    const float* g2 = (const float*)d_in[5];
    const float* b2 = (const float*)d_in[6];
    float* out = (float*)d_out;

    char* ws = (char*)d_ws;
    size_t off = 0;
    auto alloc = [&](size_t nbytes) { char* pp = ws + off; off = (off + nbytes + 255) & ~(size_t)255; return pp; };
    int8_t*   apad  = (int8_t*)alloc((size_t)PADPIX*CH);           // 27.6 MB
    int16_t*  cnt1  = (int16_t*)alloc((size_t)NPIX*CH*2);          // 51.4 MB
    int16_t*  cnt2  = (int16_t*)alloc((size_t)NPIX*CH*2);          // 51.4 MB
    int8_t*   wq    = (int8_t*)alloc((size_t)2*WQ_CONV);           // 1.2 MB
    float*    alpha = (float*)alloc((size_t)2*CH*4);
    long long* sums8 = (long long*)alloc((size_t)2*8*512*8);       // 64 KB
    float*    ab    = (float*)alloc((size_t)2*2*CH*4);             // [a1,b1 | a2,b2]

    init_kernel<<<32, 256, 0, stream>>>(sums8);
    wqpack_kernel<<<dim3(144, 2), 256, 0, stream>>>(w1, w2, wq);
    alpha_kernel<<<dim3(CH, 2), 256, 0, stream>>>(w1, w2, alpha);
    pack_x_kernel<<<(PADPIX + 255)/256, 256, 0, stream>>>(x, apad);

    conv_kernel<<<784, 256, 0, stream>>>(apad, wq, cnt1, sums8);
    bncoef_kernel<<<1, CH, 0, stream>>>(sums8, alpha, g1, b1, ab);

    conv2_kernel<<<784, 256, 0, stream>>>(cnt1, ab, wq + WQ_CONV, cnt2, sums8 + 8*512);
    bncoef_kernel<<<1, CH, 0, stream>>>(sums8 + 8*512, alpha + CH, g2, b2, ab + 2*CH);

    final_kernel<<<1568, 256, 0, stream>>>(cnt2, x, ab + 2*CH, out);
}

// Round 16
// 237.959 us; speedup vs baseline: 1.0071x; 1.0071x over previous
//
#include <hip/hip_runtime.h>
#include <stdint.h>

// Problem constants (N,C,H,W fixed by the reference)
#define NB 32
#define CH 256
#define HH 56
#define WW 56
#define HWSZ (HH*WW)            // 3136
#define NPIX (NB*HWSZ)          // 100352
#define HP 58
#define WP 58
#define PADPIX (NB*HP*WP)       // 107648
#define NTAPS 9
#define KKE (CH*NTAPS)          // 2304
#define NPIXD 100352.0
#define WQ_CONV (NTAPS*8*8*64*16)   // 589824 bytes of prepacked weights per conv
#define HSTRIDE 272             // halo row stride

typedef int int4v  __attribute__((ext_vector_type(4)));
typedef int int16v __attribute__((ext_vector_type(16)));
typedef unsigned int uint4v __attribute__((ext_vector_type(4)));

// ---------------- init: zero stats accumulators (8-way split) ----------------
__global__ void init_kernel(long long* __restrict__ sums8) {
    int t = blockIdx.x*256 + threadIdx.x;
    if (t < 2*8*512) sums8[t] = 0;     // 2 convs x 8 splits x 256 ch x {sum,sumsq}
}

// ---------------- prepack weights into MFMA B-fragment layout ----------------
__global__ void wqpack_kernel(const float* __restrict__ w1, const float* __restrict__ w2,
                              int8_t* __restrict__ wq) {
    int t = blockIdx.x*256 + threadIdx.x;     // 144 blocks -> 36864 threads
    int conv = blockIdx.y;
    const float* w = conv ? w2 : w1;
    int lane = t & 63;
    int g = t >> 6;                 // (tap*8+ks)*8+nb
    int nb = g & 7, h = g >> 3;
    int ks = h & 7, tap = h >> 3;
    int o = nb*32 + (lane & 31);
    int cin0 = ks*32 + (lane >> 5)*16;
    int wd[4];
    #pragma unroll
    for (int q = 0; q < 4; ++q) {
        int wv = 0;
        #pragma unroll
        for (int j = 0; j < 4; ++j) {
            float v = w[(size_t)(o*CH + cin0 + q*4 + j)*NTAPS + tap];
            int s = (v > 0.f) ? 1 : ((v < 0.f) ? -1 : 0);
            wv |= (s & 0xff) << (8*j);
        }
        wd[q] = wv;
    }
    *(int4v*)(wq + (size_t)conv*WQ_CONV + (size_t)t*16) = (int4v){wd[0], wd[1], wd[2], wd[3]};
}

// ---------------- alpha[o] = mean |w| over (I,3,3) ----------------
__global__ void alpha_kernel(const float* __restrict__ w1, const float* __restrict__ w2,
                             float* __restrict__ alpha) {
    int o = blockIdx.x; int conv = blockIdx.y;
    const float* w = conv ? w2 : w1;
    float s = 0.f;
    for (int i = threadIdx.x; i < KKE; i += 256) s += fabsf(w[(size_t)o*KKE + i]);
    for (int off = 32; off; off >>= 1) s += __shfl_down(s, off);
    __shared__ float l[4];
    int lane = threadIdx.x & 63, wv = threadIdx.x >> 6;
    if (lane == 0) l[wv] = s;
    __syncthreads();
    if (threadIdx.x == 0) alpha[conv*CH + o] = (l[0]+l[1]+l[2]+l[3]) * (1.f/KKE);
}

// ---------------- pack activations: x -> int8 sign, padded, ch-contiguous ----------------
__global__ void pack_x_kernel(const float* __restrict__ x, int8_t* __restrict__ apad) {
    int p = blockIdx.x*256 + threadIdx.x;
    if (p >= PADPIX) return;
    int n  = p / (HP*WP);
    int r  = p - n*(HP*WP);
    int hp = r / WP, wp = r - hp*WP;
    int4v* dst = (int4v*)(apad + (size_t)p*CH);
    if (hp >= 1 && hp <= HH && wp >= 1 && wp <= WW) {
        const float* xb = x + (size_t)n*CH*HWSZ + (hp-1)*WW + (wp-1);
        #pragma unroll 2
        for (int c16 = 0; c16 < 16; ++c16) {
            int wd[4];
            #pragma unroll
            for (int q = 0; q < 4; ++q) {
                int wv = 0;
                #pragma unroll
                for (int j = 0; j < 4; ++j) {
                    float v = xb[(size_t)(c16*16 + q*4 + j)*HWSZ];
                    int s = (v > 0.f) ? 1 : ((v < 0.f) ? -1 : 0);
                    wv |= (s & 0xff) << (8*j);
                }
                wd[q] = wv;
            }
            dst[c16] = (int4v){wd[0], wd[1], wd[2], wd[3]};
        }
    } else {
        int4v z = {0,0,0,0};
        #pragma unroll
        for (int c16 = 0; c16 < 16; ++c16) dst[c16] = z;
    }
}

// ---------------- int8 MFMA implicit-GEMM 3x3 conv, asm-pipelined K-loop ----------------
// 256 threads / 4 waves; block = 1 image x 8x8 pixels x 256 ch.
// 3-set register ring, prefetch distance 2; volatile-asm loads + counted waitcnt
// + sched_barrier(0) make the pipeline compiler-proof (rule #18 / T3+T4+T8).
#define AOFF(IT) (((((IT)>>3)/3)*10 + (((IT)>>3)%3))*HSTRIDE + ((IT)&7)*32)

#define ISSUE_SET(IT) do { \
        int k_ = (IT) % 3; \
        uint32_t ao_ = (uint32_t)AOFF(IT); \
        uint32_t vo_ = voff + (uint32_t)(IT)*8192u; \
        asm volatile("ds_read_b128 %0, %1" : "=v"(as_[k_][0]) : "v"(a0addr + ao_)); \
        asm volatile("ds_read_b128 %0, %1" : "=v"(as_[k_][1]) : "v"(a1addr + ao_)); \
        asm volatile("buffer_load_dwordx4 %0, %1, %2, 0 offen" \
                     : "=v"(bs_[k_][0]) : "v"(vo_), "s"(rsrc)); \
        asm volatile("buffer_load_dwordx4 %0, %1, %2, 0 offen offset:1024" \
                     : "=v"(bs_[k_][1]) : "v"(vo_), "s"(rsrc)); \
    } while (0)

#define CONV_BODY \
    __syncthreads(); \
    int lane = t & 63; \
    int nbp = __builtin_amdgcn_readfirstlane(t >> 6); \
    int kh = lane >> 5, lr = lane & 31; \
    int r0 = lr >> 3, c0 = lr & 7; \
    int base0 = (r0*10 + c0)*HSTRIDE + kh*16; \
    int base1 = base0 + 40*HSTRIDE; \
    uint32_t a0addr = (uint32_t)(uintptr_t)halo + (uint32_t)base0; \
    uint32_t a1addr = (uint32_t)(uintptr_t)halo + (uint32_t)base1; \
    uint32_t voff = (uint32_t)(nbp*2048 + lane*16); \
    uint4v rsrc; \
    { union { const int8_t* p; unsigned long long u; } pu_; pu_.p = wq; \
      rsrc.x = (unsigned)pu_.u; rsrc.y = (unsigned)(pu_.u >> 32); \
      rsrc.z = 0xffffffffu; rsrc.w = 0x00020000u; } \
    int4v as_[3][2], bs_[3][2]; \
    int16v acc00, acc01, acc10, acc11; \
    _Pragma("unroll") \
    for (int i = 0; i < 16; ++i) { acc00[i]=0; acc01[i]=0; acc10[i]=0; acc11[i]=0; } \
    ISSUE_SET(0); \
    ISSUE_SET(1); \
    _Pragma("unroll") \
    for (int it = 0; it < 72; ++it) { \
        if (it + 1 < 72) { asm volatile("s_waitcnt lgkmcnt(2) vmcnt(2)"); } \
        else             { asm volatile("s_waitcnt lgkmcnt(0) vmcnt(0)"); } \
        __builtin_amdgcn_sched_barrier(0); \
        if (it + 2 < 72) { ISSUE_SET(it + 2); } \
        int kc_ = it % 3; \
        acc00 = __builtin_amdgcn_mfma_i32_32x32x32_i8(as_[kc_][0], bs_[kc_][0], acc00, 0,0,0); \
        acc01 = __builtin_amdgcn_mfma_i32_32x32x32_i8(as_[kc_][0], bs_[kc_][1], acc01, 0,0,0); \
        acc10 = __builtin_amdgcn_mfma_i32_32x32x32_i8(as_[kc_][1], bs_[kc_][0], acc10, 0,0,0); \
        acc11 = __builtin_amdgcn_mfma_i32_32x32x32_i8(as_[kc_][1], bs_[kc_][1], acc11, 0,0,0); \
    } \
    { \
        int s1a = 0, s2a = 0, s1b = 0, s2b = 0; \
        _Pragma("unroll") \
        for (int reg = 0; reg < 16; ++reg) { \
            int row_ = (reg & 3) + 8*(reg >> 2) + 4*kh; \
            _Pragma("unroll") \
            for (int m = 0; m < 2; ++m) { \
                int pm_ = m*32 + row_; \
                int rr_ = pm_ >> 3, cc_ = pm_ & 7; \
                size_t pbase_ = (size_t)((n0*HH + ty*8 + rr_)*WW + tx*8 + cc_)*CH; \
                int v0 = (m ? acc10[reg] : acc00[reg]); \
                int v1 = (m ? acc11[reg] : acc01[reg]); \
                cnt[pbase_ + (nbp*2+0)*32 + lr] = (int16_t)v0; \
                cnt[pbase_ + (nbp*2+1)*32 + lr] = (int16_t)v1; \
                s1a += v0; s2a += v0*v0; s1b += v1; s2b += v1*v1; \
            } \
        } \
        s1a += __shfl_down(s1a, 32); s2a += __shfl_down(s2a, 32); \
        s1b += __shfl_down(s1b, 32); s2b += __shfl_down(s2b, 32); \
        if (lane < 32) { \
            long long* sp = sums8 + (size_t)(b & 7)*512; \
            int ch0 = nbp*64 + lr, ch1 = ch0 + 32; \
            atomicAdd((unsigned long long*)&sp[2*ch0],   (unsigned long long)(long long)s1a); \
            atomicAdd((unsigned long long*)&sp[2*ch0+1], (unsigned long long)(long long)s2a); \
            atomicAdd((unsigned long long*)&sp[2*ch1],   (unsigned long long)(long long)s1b); \
            atomicAdd((unsigned long long*)&sp[2*ch1+1], (unsigned long long)(long long)s2b); \
        } \
    }

__global__ __launch_bounds__(256, 3) void conv_kernel(
        const int8_t* __restrict__ apad, const int8_t* __restrict__ wq,
        int16_t* __restrict__ cnt, long long* __restrict__ sums8) {
    __shared__ __attribute__((aligned(16))) int8_t halo[100*HSTRIDE];   // 27.2 KB
    int b = blockIdx.x;                           // 1568 = 32 images x 49 tiles
    int tile = b % 49, n0 = b / 49;
    int ty = tile / 7, tx = tile % 7;
    int t = threadIdx.x;

    // stage halo: 100 pixels x 16 chunks of 16B (from padded int8 apad)
    #pragma unroll 1
    for (int j = 0; j < 7; ++j) {
        int idx = t + j*256;
        if (idx < 1600) {
            int pix = idx >> 4, c16 = idx & 15;
            int dr = pix / 10, dc = pix - dr*10;
            const int4v* src = (const int4v*)(apad +
                ((size_t)((n0*HP + ty*8+dr)*WP + tx*8+dc))*CH + c16*16);
            *(int4v*)&halo[pix*HSTRIDE + c16*16] = *src;
        }
    }
    CONV_BODY
}

// ---------------- conv2: same hot loop, staging fuses BN1+sign from int16 cnt1 ----------
__global__ __launch_bounds__(256, 3) void conv2_kernel(
        const int16_t* __restrict__ src16, const float* __restrict__ ab,
        const int8_t* __restrict__ wq,
        int16_t* __restrict__ cnt, long long* __restrict__ sums8) {
    __shared__ __attribute__((aligned(16))) int8_t halo[100*HSTRIDE];   // 27.2 KB
    int b = blockIdx.x;                           // 1568 = 32 images x 49 tiles
    int tile = b % 49, n0 = b / 49;
    int ty = tile / 7, tx = tile % 7;
    int t = threadIdx.x;

    // stage halo with inline BN1+sign (identical math to the old pack_s)
    {
        int c16s = t & 15;
        #pragma unroll 1
        for (int k = 0; k < 7; ++k) {
            int pix = (t >> 4) + k*16;
            if (pix < 100) {
                int dr = pix / 10, dc = pix - dr*10;
                int hi = ty*8 + dr - 1, wi = tx*8 + dc - 1;
                int4v outv = {0,0,0,0};
                if ((unsigned)hi < (unsigned)HH && (unsigned)wi < (unsigned)WW) {
                    const int16_t* sp = src16 + ((size_t)(n0*HH + hi)*WW + wi)*CH + c16s*16;
                    int4v u0 = *(const int4v*)sp;
                    int4v u1 = *(const int4v*)(sp + 8);
                    int wd[4];
                    #pragma unroll
                    for (int q = 0; q < 4; ++q) {
                        int wv = 0;
                        #pragma unroll
                        for (int j = 0; j < 4; ++j) {
                            int e = q*4 + j;
                            int word = (e < 8) ? u0[e >> 1] : u1[(e-8) >> 1];
                            int sval = (e & 1) ? (word >> 16) : ((word << 16) >> 16);
                            int ch = c16s*16 + e;
                            float v = fmaf(ab[ch], (float)sval, ab[CH + ch]);
                            int s = (v > 0.f) ? 1 : ((v < 0.f) ? -1 : 0);
                            wv |= (s & 0xff) << (8*j);
                        }
                        wd[q] = wv;
                    }
                    outv = (int4v){wd[0], wd[1], wd[2], wd[3]};
                }
                *(int4v*)&halo[pix*HSTRIDE + c16s*16] = outv;
            }
        }
    }
    CONV_BODY
}

// ---------------- BN coefficients: BN(alpha*cnt) = a*cnt + b ----------------
__global__ void bncoef_kernel(const long long* __restrict__ sums8,
                              const float* __restrict__ alpha,
                              const float* __restrict__ gamma, const float* __restrict__ beta,
                              float* __restrict__ ab) {
    int o = threadIdx.x;
    long long S1i = 0, S2i = 0;
    #pragma unroll
    for (int k = 0; k < 8; ++k) {
        S1i += sums8[(size_t)k*512 + 2*o];
        S2i += sums8[(size_t)k*512 + 2*o + 1];
    }
    double S1 = (double)S1i, S2 = (double)S2i;
    double mean = S1 / NPIXD;
    double var  = S2 / NPIXD - mean*mean;
    double al   = (double)alpha[o];
    double rs   = 1.0 / sqrt(al*al*var + 1e-5);
    double a    = (double)gamma[o] * al * rs;
    ab[o]      = (float)a;
    ab[CH + o] = (float)((double)beta[o] - a*mean);
}

// ---------------- fused epilogue: out = a2*cnt2 + b2 + x  (LDS transpose) ----------------
__global__ __launch_bounds__(256) void final_kernel(const int16_t* __restrict__ cnt,
        const float* __restrict__ x, const float* __restrict__ ab, float* __restrict__ out) {
    __shared__ int4v lsd4[64*32];                 // 64 pixels x 512B, swizzled
    int8_t* lb = (int8_t*)lsd4;
    int b = blockIdx.x;                           // 1568 = 32 n x 49 tiles
    int n = b / 49, tile = b - n*49;
    int p0 = tile * 64;
    int t = threadIdx.x;
    const int4v* src = (const int4v*)(cnt + ((size_t)n*HWSZ + p0)*CH);
    #pragma unroll
    for (int j = 0; j < 8; ++j) {
        int c = t + j*256;                        // 2048 16B-chunks
        int pix = c >> 5, c16 = c & 31;
        *(int4v*)&lb[pix*512 + ((c16*16) ^ ((pix & 15) << 4))] = src[c];
    }
    __syncthreads();
    int pixL = t & 63;
    int cb = (t >> 6) * 64;
    #pragma unroll 1
    for (int i = 0; i < 8; ++i) {
        int ch0 = cb + i*8;
        int4v v = *(const int4v*)&lb[pixL*512 + ((ch0*2) ^ ((pixL & 15) << 4))];
        #pragma unroll
        for (int j = 0; j < 8; ++j) {
            int ch = ch0 + j;
            int word = v[j >> 1];
            int sval = (j & 1) ? (word >> 16) : ((word << 16) >> 16);
            size_t g = (size_t)(n*CH + ch)*HWSZ + p0 + pixL;
            out[g] = fmaf(ab[ch], (float)sval, ab[CH + ch]) + x[g];
        }
    }
}

extern "C" void kernel_launch(void* const* d_in, const int* in_sizes, int n_in,
                              void* d_out, int out_size, void* d_ws, size_t ws_size,
                              hipStream_t stream) {
    const float* x  = (const float*)d_in[0];
    const float* w1 = (const float*)d_in[1];
    const float* g1 = (const float*)d_in[2];
    const float* b1 = (const float*)d_in[3];
    const float* w2 = (const float*)d_in[4];
    const float* g2 = (const float*)d_in[5];
    const float* b2 = (const float*)d_in[6];
    float* out = (float*)d_out;

    char* ws = (char*)d_ws;
    size_t off = 0;
    auto alloc = [&](size_t nbytes) { char* pp = ws + off; off = (off + nbytes + 255) & ~(size_t)255; return pp; };
    int8_t*   apad  = (int8_t*)alloc((size_t)PADPIX*CH);           // 27.6 MB
    int16_t*  cnt1  = (int16_t*)alloc((size_t)NPIX*CH*2);          // 51.4 MB
    int16_t*  cnt2  = (int16_t*)alloc((size_t)NPIX*CH*2);          // 51.4 MB
    int8_t*   wq    = (int8_t*)alloc((size_t)2*WQ_CONV);           // 1.2 MB
    float*    alpha = (float*)alloc((size_t)2*CH*4);
    long long* sums8 = (long long*)alloc((size_t)2*8*512*8);       // 64 KB
    float*    ab    = (float*)alloc((size_t)2*2*CH*4);             // [a1,b1 | a2,b2]

    init_kernel<<<32, 256, 0, stream>>>(sums8);
    wqpack_kernel<<<dim3(144, 2), 256, 0, stream>>>(w1, w2, wq);
    alpha_kernel<<<dim3(CH, 2), 256, 0, stream>>>(w1, w2, alpha);
    pack_x_kernel<<<(PADPIX + 255)/256, 256, 0, stream>>>(x, apad);

    conv_kernel<<<1568, 256, 0, stream>>>(apad, wq, cnt1, sums8);
    bncoef_kernel<<<1, CH, 0, stream>>>(sums8, alpha, g1, b1, ab);

    conv2_kernel<<<1568, 256, 0, stream>>>(cnt1, ab, wq + WQ_CONV, cnt2, sums8 + 8*512);
    bncoef_kernel<<<1, CH, 0, stream>>>(sums8 + 8*512, alpha + CH, g2, b2, ab + 2*CH);

    final_kernel<<<1568, 256, 0, stream>>>(cnt2, x, ab + 2*CH, out);
}

// Round 17
// 234.676 us; speedup vs baseline: 1.0212x; 1.0140x over previous
//
#include <hip/hip_runtime.h>
#include <stdint.h>

// Problem constants (N,C,H,W fixed by the reference)
#define NB 32
#define CH 256
#define HH 56
#define WW 56
#define HWSZ (HH*WW)            // 3136
#define NPIX (NB*HWSZ)          // 100352
#define HP 58
#define WP 58
#define PADPIX (NB*HP*WP)       // 107648
#define NTAPS 9
#define KKE (CH*NTAPS)          // 2304
#define NPIXD 100352.0
#define WQ_CONV (NTAPS*8*8*64*16)   // 589824 bytes of prepacked weights per conv
#define HSTRIDE 272             // halo row stride

typedef int int4v  __attribute__((ext_vector_type(4)));
typedef int int16v __attribute__((ext_vector_type(16)));
typedef unsigned int uint4v __attribute__((ext_vector_type(4)));

// ---------------- init: zero stats accumulators (8-way split) ----------------
__global__ void init_kernel(long long* __restrict__ sums8) {
    int t = blockIdx.x*256 + threadIdx.x;
    if (t < 2*8*512) sums8[t] = 0;     // 2 convs x 8 splits x 256 ch x {sum,sumsq}
}

// ---------------- prepack weights into MFMA B-fragment layout ----------------
__global__ void wqpack_kernel(const float* __restrict__ w1, const float* __restrict__ w2,
                              int8_t* __restrict__ wq) {
    int t = blockIdx.x*256 + threadIdx.x;     // 144 blocks -> 36864 threads
    int conv = blockIdx.y;
    const float* w = conv ? w2 : w1;
    int lane = t & 63;
    int g = t >> 6;                 // (tap*8+ks)*8+nb
    int nb = g & 7, h = g >> 3;
    int ks = h & 7, tap = h >> 3;
    int o = nb*32 + (lane & 31);
    int cin0 = ks*32 + (lane >> 5)*16;
    int wd[4];
    #pragma unroll
    for (int q = 0; q < 4; ++q) {
        int wv = 0;
        #pragma unroll
        for (int j = 0; j < 4; ++j) {
            float v = w[(size_t)(o*CH + cin0 + q*4 + j)*NTAPS + tap];
            int s = (v > 0.f) ? 1 : ((v < 0.f) ? -1 : 0);
            wv |= (s & 0xff) << (8*j);
        }
        wd[q] = wv;
    }
    *(int4v*)(wq + (size_t)conv*WQ_CONV + (size_t)t*16) = (int4v){wd[0], wd[1], wd[2], wd[3]};
}

// ---------------- alpha[o] = mean |w| over (I,3,3) ----------------
__global__ void alpha_kernel(const float* __restrict__ w1, const float* __restrict__ w2,
                             float* __restrict__ alpha) {
    int o = blockIdx.x; int conv = blockIdx.y;
    const float* w = conv ? w2 : w1;
    float s = 0.f;
    for (int i = threadIdx.x; i < KKE; i += 256) s += fabsf(w[(size_t)o*KKE + i]);
    for (int off = 32; off; off >>= 1) s += __shfl_down(s, off);
    __shared__ float l[4];
    int lane = threadIdx.x & 63, wv = threadIdx.x >> 6;
    if (lane == 0) l[wv] = s;
    __syncthreads();
    if (threadIdx.x == 0) alpha[conv*CH + o] = (l[0]+l[1]+l[2]+l[3]) * (1.f/KKE);
}

// ---------------- pack activations: x -> int8 sign, padded, ch-contiguous ----------------
__global__ void pack_x_kernel(const float* __restrict__ x, int8_t* __restrict__ apad) {
    int p = blockIdx.x*256 + threadIdx.x;
    if (p >= PADPIX) return;
    int n  = p / (HP*WP);
    int r  = p - n*(HP*WP);
    int hp = r / WP, wp = r - hp*WP;
    int4v* dst = (int4v*)(apad + (size_t)p*CH);
    if (hp >= 1 && hp <= HH && wp >= 1 && wp <= WW) {
        const float* xb = x + (size_t)n*CH*HWSZ + (hp-1)*WW + (wp-1);
        #pragma unroll 2
        for (int c16 = 0; c16 < 16; ++c16) {
            int wd[4];
            #pragma unroll
            for (int q = 0; q < 4; ++q) {
                int wv = 0;
                #pragma unroll
                for (int j = 0; j < 4; ++j) {
                    float v = xb[(size_t)(c16*16 + q*4 + j)*HWSZ];
                    int s = (v > 0.f) ? 1 : ((v < 0.f) ? -1 : 0);
                    wv |= (s & 0xff) << (8*j);
                }
                wd[q] = wv;
            }
            dst[c16] = (int4v){wd[0], wd[1], wd[2], wd[3]};
        }
    } else {
        int4v z = {0,0,0,0};
        #pragma unroll
        for (int c16 = 0; c16 < 16; ++c16) dst[c16] = z;
    }
}

// ---------------- int8 MFMA implicit-GEMM 3x3 conv, asm-pipelined K-loop ----------------
// 256 threads / 4 waves; block = 1 image x 8x8 pixels x 256 ch.
// 4-set register ring, prefetch distance 3; volatile-asm loads + counted waitcnt
// + sched_barrier(0) make the pipeline compiler-proof (rule #18 / T3+T4+T8).
#define AOFF(IT) (((((IT)>>3)/3)*10 + (((IT)>>3)%3))*HSTRIDE + ((IT)&7)*32)

#define ISSUE_SET(IT) do { \
        int k_ = (IT) % 4; \
        uint32_t ao_ = (uint32_t)AOFF(IT); \
        uint32_t vo_ = voff + (uint32_t)(IT)*8192u; \
        asm volatile("ds_read_b128 %0, %1" : "=v"(as_[k_][0]) : "v"(a0addr + ao_)); \
        asm volatile("ds_read_b128 %0, %1" : "=v"(as_[k_][1]) : "v"(a1addr + ao_)); \
        asm volatile("buffer_load_dwordx4 %0, %1, %2, 0 offen" \
                     : "=v"(bs_[k_][0]) : "v"(vo_), "s"(rsrc)); \
        asm volatile("buffer_load_dwordx4 %0, %1, %2, 0 offen offset:1024" \
                     : "=v"(bs_[k_][1]) : "v"(vo_), "s"(rsrc)); \
    } while (0)

#define CONV_BODY \
    __syncthreads(); \
    int lane = t & 63; \
    int nbp = __builtin_amdgcn_readfirstlane(t >> 6); \
    int kh = lane >> 5, lr = lane & 31; \
    int r0 = lr >> 3, c0 = lr & 7; \
    int base0 = (r0*10 + c0)*HSTRIDE + kh*16; \
    int base1 = base0 + 40*HSTRIDE; \
    uint32_t a0addr = (uint32_t)(uintptr_t)halo + (uint32_t)base0; \
    uint32_t a1addr = (uint32_t)(uintptr_t)halo + (uint32_t)base1; \
    uint32_t voff = (uint32_t)(nbp*2048 + lane*16); \
    uint4v rsrc; \
    { union { const int8_t* p; unsigned long long u; } pu_; pu_.p = wq; \
      rsrc.x = (unsigned)pu_.u; rsrc.y = (unsigned)(pu_.u >> 32); \
      rsrc.z = 0xffffffffu; rsrc.w = 0x00020000u; } \
    int4v as_[4][2], bs_[4][2]; \
    int16v acc00, acc01, acc10, acc11; \
    _Pragma("unroll") \
    for (int i = 0; i < 16; ++i) { acc00[i]=0; acc01[i]=0; acc10[i]=0; acc11[i]=0; } \
    ISSUE_SET(0); \
    ISSUE_SET(1); \
    ISSUE_SET(2); \
    _Pragma("unroll") \
    for (int it = 0; it < 72; ++it) { \
        if (it < 70)       { asm volatile("s_waitcnt lgkmcnt(4) vmcnt(4)"); } \
        else if (it == 70) { asm volatile("s_waitcnt lgkmcnt(2) vmcnt(2)"); } \
        else               { asm volatile("s_waitcnt lgkmcnt(0) vmcnt(0)"); } \
        __builtin_amdgcn_sched_barrier(0); \
        if (it + 3 < 72) { ISSUE_SET(it + 3); } \
        int kc_ = it % 4; \
        acc00 = __builtin_amdgcn_mfma_i32_32x32x32_i8(as_[kc_][0], bs_[kc_][0], acc00, 0,0,0); \
        acc01 = __builtin_amdgcn_mfma_i32_32x32x32_i8(as_[kc_][0], bs_[kc_][1], acc01, 0,0,0); \
        acc10 = __builtin_amdgcn_mfma_i32_32x32x32_i8(as_[kc_][1], bs_[kc_][0], acc10, 0,0,0); \
        acc11 = __builtin_amdgcn_mfma_i32_32x32x32_i8(as_[kc_][1], bs_[kc_][1], acc11, 0,0,0); \
    } \
    { \
        int s1a = 0, s2a = 0, s1b = 0, s2b = 0; \
        _Pragma("unroll") \
        for (int reg = 0; reg < 16; ++reg) { \
            int row_ = (reg & 3) + 8*(reg >> 2) + 4*kh; \
            _Pragma("unroll") \
            for (int m = 0; m < 2; ++m) { \
                int pm_ = m*32 + row_; \
                int rr_ = pm_ >> 3, cc_ = pm_ & 7; \
                size_t pbase_ = (size_t)((n0*HH + ty*8 + rr_)*WW + tx*8 + cc_)*CH; \
                int v0 = (m ? acc10[reg] : acc00[reg]); \
                int v1 = (m ? acc11[reg] : acc01[reg]); \
                cnt[pbase_ + (nbp*2+0)*32 + lr] = (int16_t)v0; \
                cnt[pbase_ + (nbp*2+1)*32 + lr] = (int16_t)v1; \
                s1a += v0; s2a += v0*v0; s1b += v1; s2b += v1*v1; \
            } \
        } \
        s1a += __shfl_down(s1a, 32); s2a += __shfl_down(s2a, 32); \
        s1b += __shfl_down(s1b, 32); s2b += __shfl_down(s2b, 32); \
        if (lane < 32) { \
            long long* sp = sums8 + (size_t)(b & 7)*512; \
            int ch0 = nbp*64 + lr, ch1 = ch0 + 32; \
            atomicAdd((unsigned long long*)&sp[2*ch0],   (unsigned long long)(long long)s1a); \
            atomicAdd((unsigned long long*)&sp[2*ch0+1], (unsigned long long)(long long)s2a); \
            atomicAdd((unsigned long long*)&sp[2*ch1],   (unsigned long long)(long long)s1b); \
            atomicAdd((unsigned long long*)&sp[2*ch1+1], (unsigned long long)(long long)s2b); \
        } \
    }

__global__ __launch_bounds__(256, 3) void conv_kernel(
        const int8_t* __restrict__ apad, const int8_t* __restrict__ wq,
        int16_t* __restrict__ cnt, long long* __restrict__ sums8) {
    __shared__ __attribute__((aligned(16))) int8_t halo[100*HSTRIDE];   // 27.2 KB
    int b = blockIdx.x;                           // 1568 = 32 images x 49 tiles
    int tile = b % 49, n0 = b / 49;
    int ty = tile / 7, tx = tile % 7;
    int t = threadIdx.x;

    // stage halo: 100 pixels x 16 chunks of 16B (from padded int8 apad)
    #pragma unroll 1
    for (int j = 0; j < 7; ++j) {
        int idx = t + j*256;
        if (idx < 1600) {
            int pix = idx >> 4, c16 = idx & 15;
            int dr = pix / 10, dc = pix - dr*10;
            const int4v* src = (const int4v*)(apad +
                ((size_t)((n0*HP + ty*8+dr)*WP + tx*8+dc))*CH + c16*16);
            *(int4v*)&halo[pix*HSTRIDE + c16*16] = *src;
        }
    }
    CONV_BODY
}

// ---------------- conv2: same hot loop, staging fuses BN1+sign from int16 cnt1 ----------
__global__ __launch_bounds__(256, 3) void conv2_kernel(
        const int16_t* __restrict__ src16, const float* __restrict__ ab,
        const int8_t* __restrict__ wq,
        int16_t* __restrict__ cnt, long long* __restrict__ sums8) {
    __shared__ __attribute__((aligned(16))) int8_t halo[100*HSTRIDE];   // 27.2 KB
    int b = blockIdx.x;                           // 1568 = 32 images x 49 tiles
    int tile = b % 49, n0 = b / 49;
    int ty = tile / 7, tx = tile % 7;
    int t = threadIdx.x;

    // stage halo with inline BN1+sign (identical math to the old pack_s)
    {
        int c16s = t & 15;
        #pragma unroll 1
        for (int k = 0; k < 7; ++k) {
            int pix = (t >> 4) + k*16;
            if (pix < 100) {
                int dr = pix / 10, dc = pix - dr*10;
                int hi = ty*8 + dr - 1, wi = tx*8 + dc - 1;
                int4v outv = {0,0,0,0};
                if ((unsigned)hi < (unsigned)HH && (unsigned)wi < (unsigned)WW) {
                    const int16_t* sp = src16 + ((size_t)(n0*HH + hi)*WW + wi)*CH + c16s*16;
                    int4v u0 = *(const int4v*)sp;
                    int4v u1 = *(const int4v*)(sp + 8);
                    int wd[4];
                    #pragma unroll
                    for (int q = 0; q < 4; ++q) {
                        int wv = 0;
                        #pragma unroll
                        for (int j = 0; j < 4; ++j) {
                            int e = q*4 + j;
                            int word = (e < 8) ? u0[e >> 1] : u1[(e-8) >> 1];
                            int sval = (e & 1) ? (word >> 16) : ((word << 16) >> 16);
                            int ch = c16s*16 + e;
                            float v = fmaf(ab[ch], (float)sval, ab[CH + ch]);
                            int s = (v > 0.f) ? 1 : ((v < 0.f) ? -1 : 0);
                            wv |= (s & 0xff) << (8*j);
                        }
                        wd[q] = wv;
                    }
                    outv = (int4v){wd[0], wd[1], wd[2], wd[3]};
                }
                *(int4v*)&halo[pix*HSTRIDE + c16s*16] = outv;
            }
        }
    }
    CONV_BODY
}

// ---------------- BN coefficients: BN(alpha*cnt) = a*cnt + b ----------------
__global__ void bncoef_kernel(const long long* __restrict__ sums8,
                              const float* __restrict__ alpha,
                              const float* __restrict__ gamma, const float* __restrict__ beta,
                              float* __restrict__ ab) {
    int o = threadIdx.x;
    long long S1i = 0, S2i = 0;
    #pragma unroll
    for (int k = 0; k < 8; ++k) {
        S1i += sums8[(size_t)k*512 + 2*o];
        S2i += sums8[(size_t)k*512 + 2*o + 1];
    }
    double S1 = (double)S1i, S2 = (double)S2i;
    double mean = S1 / NPIXD;
    double var  = S2 / NPIXD - mean*mean;
    double al   = (double)alpha[o];
    double rs   = 1.0 / sqrt(al*al*var + 1e-5);
    double a    = (double)gamma[o] * al * rs;
    ab[o]      = (float)a;
    ab[CH + o] = (float)((double)beta[o] - a*mean);
}

// ---------------- fused epilogue: out = a2*cnt2 + b2 + x  (LDS transpose) ----------------
__global__ __launch_bounds__(256) void final_kernel(const int16_t* __restrict__ cnt,
        const float* __restrict__ x, const float* __restrict__ ab, float* __restrict__ out) {
    __shared__ int4v lsd4[64*32];                 // 64 pixels x 512B, swizzled
    int8_t* lb = (int8_t*)lsd4;
    int b = blockIdx.x;                           // 1568 = 32 n x 49 tiles
    int n = b / 49, tile = b - n*49;
    int p0 = tile * 64;
    int t = threadIdx.x;
    const int4v* src = (const int4v*)(cnt + ((size_t)n*HWSZ + p0)*CH);
    #pragma unroll
    for (int j = 0; j < 8; ++j) {
        int c = t + j*256;                        // 2048 16B-chunks
        int pix = c >> 5, c16 = c & 31;
        *(int4v*)&lb[pix*512 + ((c16*16) ^ ((pix & 15) << 4))] = src[c];
    }
    __syncthreads();
    int pixL = t & 63;
    int cb = (t >> 6) * 64;
    #pragma unroll 1
    for (int i = 0; i < 8; ++i) {
        int ch0 = cb + i*8;
        int4v v = *(const int4v*)&lb[pixL*512 + ((ch0*2) ^ ((pixL & 15) << 4))];
        #pragma unroll
        for (int j = 0; j < 8; ++j) {
            int ch = ch0 + j;
            int word = v[j >> 1];
            int sval = (j & 1) ? (word >> 16) : ((word << 16) >> 16);
            size_t g = (size_t)(n*CH + ch)*HWSZ + p0 + pixL;
            out[g] = fmaf(ab[ch], (float)sval, ab[CH + ch]) + x[g];
        }
    }
}

extern "C" void kernel_launch(void* const* d_in, const int* in_sizes, int n_in,
                              void* d_out, int out_size, void* d_ws, size_t ws_size,
                              hipStream_t stream) {
    const float* x  = (const float*)d_in[0];
    const float* w1 = (const float*)d_in[1];
    const float* g1 = (const float*)d_in[2];
    const float* b1 = (const float*)d_in[3];
    const float* w2 = (const float*)d_in[4];
    const float* g2 = (const float*)d_in[5];
    const float* b2 = (const float*)d_in[6];
    float* out = (float*)d_out;

    char* ws = (char*)d_ws;
    size_t off = 0;
    auto alloc = [&](size_t nbytes) { char* pp = ws + off; off = (off + nbytes + 255) & ~(size_t)255; return pp; };
    int8_t*   apad  = (int8_t*)alloc((size_t)PADPIX*CH);           // 27.6 MB
    int16_t*  cnt1  = (int16_t*)alloc((size_t)NPIX*CH*2);          // 51.4 MB
    int16_t*  cnt2  = (int16_t*)alloc((size_t)NPIX*CH*2);          // 51.4 MB
    int8_t*   wq    = (int8_t*)alloc((size_t)2*WQ_CONV);           // 1.2 MB
    float*    alpha = (float*)alloc((size_t)2*CH*4);
    long long* sums8 = (long long*)alloc((size_t)2*8*512*8);       // 64 KB
    float*    ab    = (float*)alloc((size_t)2*2*CH*4);             // [a1,b1 | a2,b2]

    init_kernel<<<32, 256, 0, stream>>>(sums8);
    wqpack_kernel<<<dim3(144, 2), 256, 0, stream>>>(w1, w2, wq);
    alpha_kernel<<<dim3(CH, 2), 256, 0, stream>>>(w1, w2, alpha);
    pack_x_kernel<<<(PADPIX + 255)/256, 256, 0, stream>>>(x, apad);

    conv_kernel<<<1568, 256, 0, stream>>>(apad, wq, cnt1, sums8);
    bncoef_kernel<<<1, CH, 0, stream>>>(sums8, alpha, g1, b1, ab);

    conv2_kernel<<<1568, 256, 0, stream>>>(cnt1, ab, wq + WQ_CONV, cnt2, sums8 + 8*512);
    bncoef_kernel<<<1, CH, 0, stream>>>(sums8 + 8*512, alpha + CH, g2, b2, ab + 2*CH);

    final_kernel<<<1568, 256, 0, stream>>>(cnt2, x, ab + 2*CH, out);
}